// Round 4
// baseline (451.115 us; speedup 1.0000x reference)
//
#include <hip/hip_runtime.h>
#include <hip/hip_bf16.h>

typedef __bf16 bf16;
typedef __attribute__((ext_vector_type(8))) __bf16 bf16x8;
typedef __attribute__((ext_vector_type(4))) float f32x4;

static_assert(sizeof(bf16x8) == 16, "bf16x8 must be 16B");

constexpr int N_NODES = 10000;
constexpr int N_EDGES = 320000;
constexpr int KPAD    = 264;   // LDS row stride (bf16): 528B/row -> 2-way bank aliasing (free per m136)

__device__ __forceinline__ float silu_f(float x) { return x / (1.0f + __expf(-x)); }

// pack two f32 -> (bf16(lo), bf16(hi)) in one u32 via HW packed convert (RNE), 1 inst vs 3.
__device__ __forceinline__ unsigned pk_bf16(float lo, float hi) {
  unsigned r;
  asm("v_cvt_pk_bf16_f32 %0, %1, %2" : "=v"(r) : "v"(lo), "v"(hi));
  return r;
}

// ---- transposed-output MFMA: acc[mi][ni] = WT-rows x rows-of-Albs (4x4 tile, 64 cols).
// D row(q*4+reg) = out channel (w*64+16*mi+4q+rg), D col(lane&15) = col-row (16*ni+r).
__device__ __forceinline__ void mfmaT_k256(const bf16* __restrict__ WT, int wstride, int koff,
                                           const bf16* Albs, int w, int r, int q, f32x4 acc[4][4]) {
  for (int k0 = 0; k0 < 256; k0 += 32) {
    bf16x8 a[4], b[4];
#pragma unroll
    for (int mi = 0; mi < 4; ++mi)
      a[mi] = *(const bf16x8*)(WT + (size_t)(w * 64 + 16 * mi + r) * wstride + koff + k0 + q * 8);
#pragma unroll
    for (int ni = 0; ni < 4; ++ni)
      b[ni] = *(const bf16x8*)(Albs + (16 * ni + r) * KPAD + k0 + q * 8);
#pragma unroll
    for (int mi = 0; mi < 4; ++mi)
#pragma unroll
      for (int ni = 0; ni < 4; ++ni)
        acc[mi][ni] = __builtin_amdgcn_mfma_f32_16x16x32_bf16(a[mi], b[ni], acc[mi][ni], 0, 0, 0);
  }
}

// ---- 4x2 variant (32-col tiles, node/gemm_pq splits)
__device__ __forceinline__ void mfmaT_k256_b2(const bf16* __restrict__ WT, int wstride, int koff,
                                              const bf16* Albs, int w, int r, int q, f32x4 acc[4][2]) {
  for (int k0 = 0; k0 < 256; k0 += 32) {
    bf16x8 a[4], b[2];
#pragma unroll
    for (int ni = 0; ni < 2; ++ni)
      b[ni] = *(const bf16x8*)(Albs + (16 * ni + r) * KPAD + k0 + q * 8);
#pragma unroll
    for (int mi = 0; mi < 4; ++mi)
      a[mi] = *(const bf16x8*)(WT + (size_t)(w * 64 + 16 * mi + r) * wstride + koff + k0 + q * 8);
#pragma unroll
    for (int mi = 0; mi < 4; ++mi)
#pragma unroll
      for (int ni = 0; ni < 2; ++ni)
        acc[mi][ni] = __builtin_amdgcn_mfma_f32_16x16x32_bf16(a[mi], b[ni], acc[mi][ni], 0, 0, 0);
  }
}

// ---- prep (+fused hist): h -> bf16; weights -> bf16 transposed [n][k]; histogram of rows
__global__ __launch_bounds__(256) void prep_kernel(
    const float* __restrict__ h, const float* __restrict__ We1, const float* __restrict__ We2,
    const float* __restrict__ Wn1, const float* __restrict__ Wn2, const float* __restrict__ Wc1,
    const int* __restrict__ eidx,
    bf16* __restrict__ Hb, bf16* __restrict__ We1T, bf16* __restrict__ Wn1T,
    bf16* __restrict__ We2T, bf16* __restrict__ Wn2T, bf16* __restrict__ Wc1T,
    int* __restrict__ hist) {
  int bid = blockIdx.x, tid = threadIdx.x;
  if (bid < 10000) { int i = bid * 256 + tid; Hb[i] = (bf16)h[i]; return; }
  if (bid >= 11792) {
    int e = (bid - 11792) * 256 + tid;
    if (e < N_EDGES) atomicAdd(&hist[eidx[e]], 1);
    return;
  }
  int t = (bid - 10000) * 256 + tid;
  if (t < 131072) { int k = t >> 8, j = t & 255; We1T[j * 512 + k] = (bf16)We1[k * 256 + j]; return; }
  t -= 131072;
  if (t < 131072) { int k = t >> 8, j = t & 255; Wn1T[j * 512 + k] = (bf16)Wn1[k * 256 + j]; return; }
  t -= 131072;
  if (t < 65536) { int k = t >> 8, j = t & 255; We2T[j * 256 + k] = (bf16)We2[k * 256 + j]; return; }
  t -= 65536;
  if (t < 65536) { int k = t >> 8, j = t & 255; Wn2T[j * 256 + k] = (bf16)Wn2[k * 256 + j]; return; }
  t -= 65536;
  if (t < 65536) { int k = t >> 8, j = t & 255; Wc1T[j * 256 + k] = (bf16)Wc1[k * 256 + j]; return; }
}

// ---- scan (parallel Hillis-Steele over 256 partials)
__global__ __launch_bounds__(256) void scan_kernel(const int* __restrict__ hist,
                                                   int* __restrict__ base, int* __restrict__ cursor) {
  __shared__ int partial[256];
  int t = threadIdx.x;
  int s = 0;
  for (int i = 0; i < 40; ++i) { int idx = t * 40 + i; if (idx < N_NODES) s += hist[idx]; }
  partial[t] = s;
  __syncthreads();
  for (int d = 1; d < 256; d <<= 1) {
    int v = (t >= d) ? partial[t - d] : 0;
    __syncthreads();
    partial[t] += v;
    __syncthreads();
  }
  int run = partial[t] - s;  // exclusive
  for (int i = 0; i < 40; ++i) {
    int idx = t * 40 + i;
    if (idx < N_NODES) { base[idx] = run; cursor[idx] = run; run += hist[idx]; }
  }
}

__global__ __launch_bounds__(256) void scatter_kernel(const int* __restrict__ eidx, int* __restrict__ cursor,
                                                      int* __restrict__ rs, int* __restrict__ cs) {
  int e = blockIdx.x * 256 + threadIdx.x;
  if (e < N_EDGES) {
    int r = eidx[e], c = eidx[N_EDGES + e];
    int p = atomicAdd(&cursor[r], 1);
    rs[p] = r; cs[p] = c;
  }
}

// ---- P/Q GEMM -> f32 outputs (kills bf16 cvts in edge e1 phase). P gets be1 folded in.
// 32-node tiles (dim3(313,2)) to halve single-block critical path (this launch is ~1 block/CU).
__global__ __launch_bounds__(256, 2) void gemm_pq(const bf16* __restrict__ Hb,
                                                  const bf16* __restrict__ We1T,
                                                  const float* __restrict__ be1,
                                                  float* __restrict__ P, float* __restrict__ Q) {
  int tid = threadIdx.x, w = tid >> 6, lane = tid & 63, r = lane & 15, q = lane >> 4;
  int m0 = blockIdx.x * 32;
  int koff = blockIdx.y ? 256 : 0;
  float* OUT = blockIdx.y ? Q : P;
  bool addb = (blockIdx.y == 0);
  f32x4 acc[4][2];
#pragma unroll
  for (int mi = 0; mi < 4; ++mi)
#pragma unroll
    for (int ni = 0; ni < 2; ++ni) acc[mi][ni] = (f32x4){0.f, 0.f, 0.f, 0.f};

  for (int k0 = 0; k0 < 256; k0 += 32) {
    bf16x8 a[4], b[2];
#pragma unroll
    for (int mi = 0; mi < 4; ++mi)
      a[mi] = *(const bf16x8*)(We1T + (size_t)(w * 64 + 16 * mi + r) * 512 + koff + k0 + q * 8);
#pragma unroll
    for (int ni = 0; ni < 2; ++ni) {
      int m = m0 + 16 * ni + r; if (m > N_NODES - 1) m = N_NODES - 1;
      b[ni] = *(const bf16x8*)(Hb + (size_t)m * 256 + k0 + q * 8);
    }
#pragma unroll
    for (int mi = 0; mi < 4; ++mi)
#pragma unroll
      for (int ni = 0; ni < 2; ++ni)
        acc[mi][ni] = __builtin_amdgcn_mfma_f32_16x16x32_bf16(a[mi], b[ni], acc[mi][ni], 0, 0, 0);
  }
#pragma unroll
  for (int mi = 0; mi < 4; ++mi) {
    int ch = w * 64 + 16 * mi + 4 * q;
    float4 bv = addb ? *(const float4*)(be1 + ch) : (float4){0.f, 0.f, 0.f, 0.f};
#pragma unroll
    for (int ni = 0; ni < 2; ++ni) {
      int m = m0 + 16 * ni + r;
      if (m < N_NODES) {
        float4 o;
        o.x = acc[mi][ni][0] + bv.x;
        o.y = acc[mi][ni][1] + bv.y;
        o.z = acc[mi][ni][2] + bv.z;
        o.w = acc[mi][ni][3] + bv.w;
        *(float4*)(OUT + (size_t)m * 256 + ch) = o;
      }
    }
  }
}

// ---- edge kernel: 64 sorted edges/block, transposed GEMMs, fused coord-MLP epilogue,
// f32 P/Q gathers (no bf16->f32 cvts in the e1 hot loop).
__global__ __launch_bounds__(256, 4) void edge_kernel(
    const float* __restrict__ coord, const int* __restrict__ rs, const int* __restrict__ cs,
    const float* __restrict__ We1,
    const float* __restrict__ be2, const float* __restrict__ bc1,
    const float* __restrict__ Wc2, const float* __restrict__ bc2,
    const float* __restrict__ P, const float* __restrict__ Q,
    const bf16* __restrict__ We2T, const bf16* __restrict__ Wc1T,
    float* __restrict__ agg_h, float* __restrict__ agg_c) {
  __shared__ __align__(16) bf16 buf[64 * KPAD];
  __shared__ int s_row[64], s_col[64];
  __shared__ float s_rad[64], s_cd[64][3], s_part[64][4], s_scal[64];
  __shared__ int s_rs[65];
  __shared__ int s_nrun;

  int tid = threadIdx.x;
  int e0 = blockIdx.x * 64;
  int w = tid >> 6, lane = tid & 63, r = lane & 15, q = lane >> 4;

  if (tid < 64) {
    int e = e0 + tid;
    int ri = rs[e], ci = cs[e];
    s_row[tid] = ri; s_col[tid] = ci;
    float dx = coord[3 * ri + 0] - coord[3 * ci + 0];
    float dy = coord[3 * ri + 1] - coord[3 * ci + 1];
    float dz = coord[3 * ri + 2] - coord[3 * ci + 2];
    s_cd[tid][0] = dx; s_cd[tid][1] = dy; s_cd[tid][2] = dz;
    s_rad[tid] = dx * dx + dy * dy + dz * dz;
  }
  __syncthreads();

  // wave 0: run boundaries of sorted rows (avg 2-3 runs/block)
  if (tid < 64) {
    bool bnd = (tid == 0) || (s_row[tid] != s_row[tid - 1]);
    unsigned long long m = __ballot(bnd);
    int rank = __popcll(m & ((1ull << tid) - 1ull));
    if (bnd) s_rs[rank] = tid;
    if (tid == 0) { int R = __popcll(m); s_nrun = R; s_rs[R] = 64; }
  }

  // e1 = silu(P[row] + Q[col] + radial*We1[512]) -> buf (be1 pre-folded into P); all f32 in.
  {
    int off = (tid & 31) * 8;
    int esub = tid >> 5;
    float4 wa = *(const float4*)(We1 + 512 * 256 + off);
    float4 wb = *(const float4*)(We1 + 512 * 256 + off + 4);
#pragma unroll
    for (int p = 0; p < 8; ++p) {
      int e = p * 8 + esub;
      int ri = s_row[e], ci = s_col[e];
      const float* pp = P + (size_t)ri * 256 + off;
      const float* qp = Q + (size_t)ci * 256 + off;
      float4 p0 = *(const float4*)pp;
      float4 p1 = *(const float4*)(pp + 4);
      float4 q0 = *(const float4*)qp;
      float4 q1 = *(const float4*)(qp + 4);
      float rad = s_rad[e];
      float f0 = silu_f(p0.x + q0.x + rad * wa.x);
      float f1 = silu_f(p0.y + q0.y + rad * wa.y);
      float f2 = silu_f(p0.z + q0.z + rad * wa.z);
      float f3 = silu_f(p0.w + q0.w + rad * wa.w);
      float f4 = silu_f(p1.x + q1.x + rad * wb.x);
      float f5 = silu_f(p1.y + q1.y + rad * wb.y);
      float f6 = silu_f(p1.z + q1.z + rad * wb.z);
      float f7 = silu_f(p1.w + q1.w + rad * wb.w);
      uint4 o;
      o.x = pk_bf16(f0, f1); o.y = pk_bf16(f2, f3);
      o.z = pk_bf16(f4, f5); o.w = pk_bf16(f6, f7);
      *(uint4*)(buf + e * KPAD + off) = o;
    }
  }
  __syncthreads();

  // GEMM1-T: edge_feat: acc rows = We2 out-channels, cols = edges
  {
    f32x4 acc[4][4];
#pragma unroll
    for (int mi = 0; mi < 4; ++mi)
#pragma unroll
      for (int ni = 0; ni < 4; ++ni) acc[mi][ni] = (f32x4){0.f, 0.f, 0.f, 0.f};
    mfmaT_k256(We2T, 256, 0, buf, w, r, q, acc);
    __syncthreads();   // all reads of e1 done before overwrite
#pragma unroll
    for (int mi = 0; mi < 4; ++mi) {
      int ch = w * 64 + 16 * mi + 4 * q;
      float4 bv = *(const float4*)(be2 + ch);
#pragma unroll
      for (int ni = 0; ni < 4; ++ni) {
        int edge = 16 * ni + r;
        float f0 = silu_f(acc[mi][ni][0] + bv.x);
        float f1 = silu_f(acc[mi][ni][1] + bv.y);
        float f2 = silu_f(acc[mi][ni][2] + bv.z);
        float f3 = silu_f(acc[mi][ni][3] + bv.w);
        uint2 o; o.x = pk_bf16(f0, f1); o.y = pk_bf16(f2, f3);
        *(uint2*)(buf + edge * KPAD + ch) = o;  // buf[edge][ch], b64 write
      }
    }
  }
  __syncthreads();

  // GEMM2-T k-loop (reads edge_feat) ...
  f32x4 acc2[4][4];
#pragma unroll
  for (int mi = 0; mi < 4; ++mi)
#pragma unroll
    for (int ni = 0; ni < 4; ++ni) acc2[mi][ni] = (f32x4){0.f, 0.f, 0.f, 0.f};
  mfmaT_k256(Wc1T, 256, 0, buf, w, r, q, acc2);

  // ... interleaved with run-based agg_h column sums (also reads edge_feat)
  {
    int R = s_nrun;
    for (int rr = 0; rr < R; ++rr) {
      int st = s_rs[rr], en = s_rs[rr + 1];
      float s = 0.f;
      for (int e = st; e < en; ++e) s += (float)buf[e * KPAD + tid];
      atomicAdd(&agg_h[(size_t)s_row[st] * 256 + tid], s);
    }
  }

  // GEMM2 fused epilogue: scalar partials p[edge] = sum_ch silu(c1)*Wc2[ch],
  // computed straight from acc2 registers (c1 never written to LDS).
  {
    float p[4] = {0.f, 0.f, 0.f, 0.f};
#pragma unroll
    for (int mi = 0; mi < 4; ++mi) {
      int ch = w * 64 + 16 * mi + 4 * q;
      float4 bv = *(const float4*)(bc1 + ch);
      float4 wv = *(const float4*)(Wc2 + ch);
#pragma unroll
      for (int ni = 0; ni < 4; ++ni) {
        p[ni] += silu_f(acc2[mi][ni][0] + bv.x) * wv.x
               + silu_f(acc2[mi][ni][1] + bv.y) * wv.y
               + silu_f(acc2[mi][ni][2] + bv.z) * wv.z
               + silu_f(acc2[mi][ni][3] + bv.w) * wv.w;
      }
    }
    // reduce over the 4 q-lane-groups (lanes r, r+16, r+32, r+48 hold the same edge)
#pragma unroll
    for (int ni = 0; ni < 4; ++ni) {
      float v = p[ni];
      v += __shfl_xor(v, 16, 64);
      v += __shfl_xor(v, 32, 64);
      if (q == 0) s_part[16 * ni + r][w] = v;
    }
  }
  __syncthreads();   // s_part ready (agg_h atomics need no barrier)

  if (tid < 64)
    s_scal[tid] = s_part[tid][0] + s_part[tid][1] + s_part[tid][2] + s_part[tid][3] + bc2[0];
  __syncthreads();

  // coord aggregation: run-based, one lane per xyz component
  if (tid < 3) {
    int R = s_nrun;
    for (int rr = 0; rr < R; ++rr) {
      int st = s_rs[rr], en = s_rs[rr + 1];
      float s = 0.f;
      for (int e = st; e < en; ++e) s += s_cd[e][tid] * s_scal[e];
      atomicAdd(&agg_c[3 * s_row[st] + tid], s);
    }
  }
}

// ---- node kernel (fused post): coord_out + agg->bf16 inline + 2-layer node MLP.
// 32-node tiles (313 blocks) to halve single-block critical path (~1 block/CU launch).
__global__ __launch_bounds__(256, 2) void node_kernel(
    const bf16* __restrict__ Hb, const float* __restrict__ agg_h,
    const int* __restrict__ hist, const float* __restrict__ coord, const float* __restrict__ agg_c,
    const bf16* __restrict__ Wn1T, const bf16* __restrict__ Wn2T,
    const float* __restrict__ bn1, const float* __restrict__ bn2,
    float* __restrict__ h_out, float* __restrict__ coord_out) {
  __shared__ __align__(16) bf16 buf[32 * KPAD];
  int tid = threadIdx.x, w = tid >> 6, lane = tid & 63, r = lane & 15, q = lane >> 4;
  int m0 = blockIdx.x * 32;

  // coord_out
  if (tid < 32) {
    int m = m0 + tid;
    if (m < N_NODES) {
      float c = (float)hist[m]; if (c < 1.f) c = 1.f;
      coord_out[3 * m + 0] = coord[3 * m + 0] + agg_c[3 * m + 0] / c;
      coord_out[3 * m + 1] = coord[3 * m + 1] + agg_c[3 * m + 1] / c;
      coord_out[3 * m + 2] = coord[3 * m + 2] + agg_c[3 * m + 2] / c;
    }
  }

  // layer1: rows = hidden channels, cols = nodes (32)
  f32x4 acc[4][2];
#pragma unroll
  for (int mi = 0; mi < 4; ++mi)
#pragma unroll
    for (int ni = 0; ni < 2; ++ni) acc[mi][ni] = (f32x4){0.f, 0.f, 0.f, 0.f};
  // part A: h (k 0..255), B from Hb global
  for (int k0 = 0; k0 < 256; k0 += 32) {
    bf16x8 a[4], b[2];
#pragma unroll
    for (int mi = 0; mi < 4; ++mi)
      a[mi] = *(const bf16x8*)(Wn1T + (size_t)(w * 64 + 16 * mi + r) * 512 + k0 + q * 8);
#pragma unroll
    for (int ni = 0; ni < 2; ++ni) {
      int m = m0 + 16 * ni + r; if (m > N_NODES - 1) m = N_NODES - 1;
      b[ni] = *(const bf16x8*)(Hb + (size_t)m * 256 + k0 + q * 8);
    }
#pragma unroll
    for (int mi = 0; mi < 4; ++mi)
#pragma unroll
      for (int ni = 0; ni < 2; ++ni)
        acc[mi][ni] = __builtin_amdgcn_mfma_f32_16x16x32_bf16(a[mi], b[ni], acc[mi][ni], 0, 0, 0);
  }
  // part B: agg_h f32 -> bf16 on the fly (k 256..511)
  for (int k0 = 0; k0 < 256; k0 += 32) {
    bf16x8 a[4], b[2];
#pragma unroll
    for (int mi = 0; mi < 4; ++mi)
      a[mi] = *(const bf16x8*)(Wn1T + (size_t)(w * 64 + 16 * mi + r) * 512 + 256 + k0 + q * 8);
#pragma unroll
    for (int ni = 0; ni < 2; ++ni) {
      int m = m0 + 16 * ni + r; if (m > N_NODES - 1) m = N_NODES - 1;
      const float* ap = agg_h + (size_t)m * 256 + k0 + q * 8;
      float4 u = *(const float4*)ap;
      float4 v = *(const float4*)(ap + 4);
      uint4 o;
      o.x = pk_bf16(u.x, u.y); o.y = pk_bf16(u.z, u.w);
      o.z = pk_bf16(v.x, v.y); o.w = pk_bf16(v.z, v.w);
      b[ni] = *(const bf16x8*)&o;
    }
#pragma unroll
    for (int mi = 0; mi < 4; ++mi)
#pragma unroll
      for (int ni = 0; ni < 2; ++ni)
        acc[mi][ni] = __builtin_amdgcn_mfma_f32_16x16x32_bf16(a[mi], b[ni], acc[mi][ni], 0, 0, 0);
  }
  __syncthreads();
  // epilogue -> buf[node_local][hidden], b64 writes
#pragma unroll
  for (int mi = 0; mi < 4; ++mi) {
    int ch = w * 64 + 16 * mi + 4 * q;
    float4 bv = *(const float4*)(bn1 + ch);
#pragma unroll
    for (int ni = 0; ni < 2; ++ni) {
      int lm = 16 * ni + r;
      float f0 = silu_f(acc[mi][ni][0] + bv.x);
      float f1 = silu_f(acc[mi][ni][1] + bv.y);
      float f2 = silu_f(acc[mi][ni][2] + bv.z);
      float f3 = silu_f(acc[mi][ni][3] + bv.w);
      uint2 o; o.x = pk_bf16(f0, f1); o.y = pk_bf16(f2, f3);
      *(uint2*)(buf + lm * KPAD + ch) = o;
    }
  }
  __syncthreads();
  // layer2 -> h_out (float4 stores)
  f32x4 acc2[4][2];
#pragma unroll
  for (int mi = 0; mi < 4; ++mi)
#pragma unroll
    for (int ni = 0; ni < 2; ++ni) acc2[mi][ni] = (f32x4){0.f, 0.f, 0.f, 0.f};
  mfmaT_k256_b2(Wn2T, 256, 0, buf, w, r, q, acc2);
#pragma unroll
  for (int mi = 0; mi < 4; ++mi) {
    int ch = w * 64 + 16 * mi + 4 * q;
    float4 bv = *(const float4*)(bn2 + ch);
#pragma unroll
    for (int ni = 0; ni < 2; ++ni) {
      int m = m0 + 16 * ni + r;
      if (m < N_NODES) {
        float4 o;
        o.x = acc2[mi][ni][0] + bv.x;
        o.y = acc2[mi][ni][1] + bv.y;
        o.z = acc2[mi][ni][2] + bv.z;
        o.w = acc2[mi][ni][3] + bv.w;
        *(float4*)(h_out + (size_t)m * 256 + ch) = o;
      }
    }
  }
}

extern "C" void kernel_launch(void* const* d_in, const int* in_sizes, int n_in,
                              void* d_out, int out_size, void* d_ws, size_t ws_size,
                              hipStream_t stream) {
  const float* h     = (const float*)d_in[0];
  const float* coord = (const float*)d_in[1];
  const int*   eidx  = (const int*)d_in[2];
  const float* We1 = (const float*)d_in[3];
  const float* be1 = (const float*)d_in[4];
  const float* We2 = (const float*)d_in[5];
  const float* be2 = (const float*)d_in[6];
  const float* Wn1 = (const float*)d_in[7];
  const float* bn1 = (const float*)d_in[8];
  const float* Wn2 = (const float*)d_in[9];
  const float* bn2 = (const float*)d_in[10];
  const float* Wc1 = (const float*)d_in[11];
  const float* bc1 = (const float*)d_in[12];
  const float* Wc2 = (const float*)d_in[13];
  const float* bc2 = (const float*)d_in[14];

  char* ws = (char*)d_ws;
  float* agg_h = (float*)(ws + 0);          // 10,240,000
  float* agg_c = (float*)(ws + 10240000);   //    120,000
  int*   hist  = (int*)  (ws + 10360000);   //     40,000
  int*   base  = (int*)  (ws + 10400000);   //     40,000
  int*   cursor= (int*)  (ws + 10440000);   //     40,000
  int*   rs    = (int*)  (ws + 10480000);   //  1,280,000
  int*   cs    = (int*)  (ws + 11760000);   //  1,280,000
  bf16*  Hb    = (bf16*) (ws + 13040000);   //  5,120,000
  float* Pf    = (float*)(ws + 18160000);   // 10,240,000
  float* Qf    = (float*)(ws + 28400000);   // 10,240,000
  bf16* We1T = (bf16*)(ws + 38640000);      //    262,144
  bf16* Wn1T = (bf16*)(ws + 38902144);      //    262,144
  bf16* We2T = (bf16*)(ws + 39164288);      //    131,072
  bf16* Wn2T = (bf16*)(ws + 39295360);      //    131,072
  bf16* Wc1T = (bf16*)(ws + 39426432);      //    131,072

  float* h_out = (float*)d_out;
  float* coord_out = h_out + (size_t)N_NODES * 256;

  hipMemsetAsync(ws, 0, 10400000, stream);  // agg_h + agg_c + hist
  prep_kernel<<<13042, 256, 0, stream>>>(h, We1, We2, Wn1, Wn2, Wc1, eidx,
                                         Hb, We1T, Wn1T, We2T, Wn2T, Wc1T, hist);
  scan_kernel<<<1, 256, 0, stream>>>(hist, base, cursor);
  scatter_kernel<<<1250, 256, 0, stream>>>(eidx, cursor, rs, cs);
  gemm_pq<<<dim3(313, 2), 256, 0, stream>>>(Hb, We1T, be1, Pf, Qf);
  edge_kernel<<<5000, 256, 0, stream>>>(coord, rs, cs, We1, be2, bc1, Wc2, bc2,
                                        Pf, Qf, We2T, Wc1T, agg_h, agg_c);
  node_kernel<<<313, 256, 0, stream>>>(Hb, agg_h, hist, coord, agg_c,
                                       Wn1T, Wn2T, bn1, bn2, h_out, coord_out);
}

// Round 5
// 421.468 us; speedup vs baseline: 1.0703x; 1.0703x over previous
//
#include <hip/hip_runtime.h>
#include <hip/hip_bf16.h>

typedef __bf16 bf16;
typedef __attribute__((ext_vector_type(8))) __bf16 bf16x8;
typedef __attribute__((ext_vector_type(4))) float f32x4;

static_assert(sizeof(bf16x8) == 16, "bf16x8 must be 16B");

constexpr int N_NODES = 10000;
constexpr int N_EDGES = 320000;
constexpr int KPAD    = 264;   // LDS row stride (bf16): 528B/row -> 2-way bank aliasing (free per m136)

// single-instruction reciprocal (~1 ulp; exact enough under bf16 rounding).
__device__ __forceinline__ float rcp_f(float x) {
  float r; asm("v_rcp_f32 %0, %1" : "=v"(r) : "v"(x)); return r;
}
// silu via rcp: 5 VALU insts vs ~11 for IEEE divide sequence. rcp(inf)=0 -> silu(-big)=0 correct.
__device__ __forceinline__ float silu_f(float x) { return x * rcp_f(1.0f + __expf(-x)); }

// pack two f32 -> (bf16(lo), bf16(hi)) in one u32 via HW packed convert (RNE).
__device__ __forceinline__ unsigned pk_bf16(float lo, float hi) {
  unsigned r;
  asm("v_cvt_pk_bf16_f32 %0, %1, %2" : "=v"(r) : "v"(lo), "v"(hi));
  return r;
}

// ---- transposed-output MFMA: acc[mi][ni] = WT-rows x rows-of-Albs (4x4 tile, 64 cols).
// D row(q*4+reg) = out channel (w*64+16*mi+4q+rg), D col(lane&15) = col-row (16*ni+r).
__device__ __forceinline__ void mfmaT_k256(const bf16* __restrict__ WT, int wstride, int koff,
                                           const bf16* Albs, int w, int r, int q, f32x4 acc[4][4]) {
  for (int k0 = 0; k0 < 256; k0 += 32) {
    bf16x8 a[4], b[4];
#pragma unroll
    for (int mi = 0; mi < 4; ++mi)
      a[mi] = *(const bf16x8*)(WT + (size_t)(w * 64 + 16 * mi + r) * wstride + koff + k0 + q * 8);
#pragma unroll
    for (int ni = 0; ni < 4; ++ni)
      b[ni] = *(const bf16x8*)(Albs + (16 * ni + r) * KPAD + k0 + q * 8);
#pragma unroll
    for (int mi = 0; mi < 4; ++mi)
#pragma unroll
      for (int ni = 0; ni < 4; ++ni)
        acc[mi][ni] = __builtin_amdgcn_mfma_f32_16x16x32_bf16(a[mi], b[ni], acc[mi][ni], 0, 0, 0);
  }
}

// ---- 4x2 variant (32-col tiles, node/gemm_pq splits)
__device__ __forceinline__ void mfmaT_k256_b2(const bf16* __restrict__ WT, int wstride, int koff,
                                              const bf16* Albs, int w, int r, int q, f32x4 acc[4][2]) {
  for (int k0 = 0; k0 < 256; k0 += 32) {
    bf16x8 a[4], b[2];
#pragma unroll
    for (int ni = 0; ni < 2; ++ni)
      b[ni] = *(const bf16x8*)(Albs + (16 * ni + r) * KPAD + k0 + q * 8);
#pragma unroll
    for (int mi = 0; mi < 4; ++mi)
      a[mi] = *(const bf16x8*)(WT + (size_t)(w * 64 + 16 * mi + r) * wstride + koff + k0 + q * 8);
#pragma unroll
    for (int mi = 0; mi < 4; ++mi)
#pragma unroll
      for (int ni = 0; ni < 2; ++ni)
        acc[mi][ni] = __builtin_amdgcn_mfma_f32_16x16x32_bf16(a[mi], b[ni], acc[mi][ni], 0, 0, 0);
  }
}

// ---- prep (+fused hist): h -> bf16; weights -> bf16 transposed [n][k]; histogram of rows
__global__ __launch_bounds__(256) void prep_kernel(
    const float* __restrict__ h, const float* __restrict__ We1, const float* __restrict__ We2,
    const float* __restrict__ Wn1, const float* __restrict__ Wn2, const float* __restrict__ Wc1,
    const int* __restrict__ eidx,
    bf16* __restrict__ Hb, bf16* __restrict__ We1T, bf16* __restrict__ Wn1T,
    bf16* __restrict__ We2T, bf16* __restrict__ Wn2T, bf16* __restrict__ Wc1T,
    int* __restrict__ hist) {
  int bid = blockIdx.x, tid = threadIdx.x;
  if (bid < 10000) { int i = bid * 256 + tid; Hb[i] = (bf16)h[i]; return; }
  if (bid >= 11792) {
    int e = (bid - 11792) * 256 + tid;
    if (e < N_EDGES) atomicAdd(&hist[eidx[e]], 1);
    return;
  }
  int t = (bid - 10000) * 256 + tid;
  if (t < 131072) { int k = t >> 8, j = t & 255; We1T[j * 512 + k] = (bf16)We1[k * 256 + j]; return; }
  t -= 131072;
  if (t < 131072) { int k = t >> 8, j = t & 255; Wn1T[j * 512 + k] = (bf16)Wn1[k * 256 + j]; return; }
  t -= 131072;
  if (t < 65536) { int k = t >> 8, j = t & 255; We2T[j * 256 + k] = (bf16)We2[k * 256 + j]; return; }
  t -= 65536;
  if (t < 65536) { int k = t >> 8, j = t & 255; Wn2T[j * 256 + k] = (bf16)Wn2[k * 256 + j]; return; }
  t -= 65536;
  if (t < 65536) { int k = t >> 8, j = t & 255; Wc1T[j * 256 + k] = (bf16)Wc1[k * 256 + j]; return; }
}

// ---- scan (parallel Hillis-Steele over 256 partials)
__global__ __launch_bounds__(256) void scan_kernel(const int* __restrict__ hist,
                                                   int* __restrict__ base, int* __restrict__ cursor) {
  __shared__ int partial[256];
  int t = threadIdx.x;
  int s = 0;
  for (int i = 0; i < 40; ++i) { int idx = t * 40 + i; if (idx < N_NODES) s += hist[idx]; }
  partial[t] = s;
  __syncthreads();
  for (int d = 1; d < 256; d <<= 1) {
    int v = (t >= d) ? partial[t - d] : 0;
    __syncthreads();
    partial[t] += v;
    __syncthreads();
  }
  int run = partial[t] - s;  // exclusive
  for (int i = 0; i < 40; ++i) {
    int idx = t * 40 + i;
    if (idx < N_NODES) { base[idx] = run; cursor[idx] = run; run += hist[idx]; }
  }
}

__global__ __launch_bounds__(256) void scatter_kernel(const int* __restrict__ eidx, int* __restrict__ cursor,
                                                      int* __restrict__ rs, int* __restrict__ cs) {
  int e = blockIdx.x * 256 + threadIdx.x;
  if (e < N_EDGES) {
    int r = eidx[e], c = eidx[N_EDGES + e];
    int p = atomicAdd(&cursor[r], 1);
    rs[p] = r; cs[p] = c;
  }
}

// ---- P/Q GEMM (transposed-output, bf16 out, be1 folded into P).
// 32-node tiles (dim3(313,2)): halves single-block critical path at ~1 block/CU.
__global__ __launch_bounds__(256, 2) void gemm_pq(const bf16* __restrict__ Hb,
                                                  const bf16* __restrict__ We1T,
                                                  const float* __restrict__ be1,
                                                  bf16* __restrict__ P, bf16* __restrict__ Q) {
  int tid = threadIdx.x, w = tid >> 6, lane = tid & 63, r = lane & 15, q = lane >> 4;
  int m0 = blockIdx.x * 32;
  int koff = blockIdx.y ? 256 : 0;
  bf16* OUT = blockIdx.y ? Q : P;
  bool addb = (blockIdx.y == 0);
  f32x4 acc[4][2];
#pragma unroll
  for (int mi = 0; mi < 4; ++mi)
#pragma unroll
    for (int ni = 0; ni < 2; ++ni) acc[mi][ni] = (f32x4){0.f, 0.f, 0.f, 0.f};

  for (int k0 = 0; k0 < 256; k0 += 32) {
    bf16x8 a[4], b[2];
#pragma unroll
    for (int mi = 0; mi < 4; ++mi)
      a[mi] = *(const bf16x8*)(We1T + (size_t)(w * 64 + 16 * mi + r) * 512 + koff + k0 + q * 8);
#pragma unroll
    for (int ni = 0; ni < 2; ++ni) {
      int m = m0 + 16 * ni + r; if (m > N_NODES - 1) m = N_NODES - 1;
      b[ni] = *(const bf16x8*)(Hb + (size_t)m * 256 + k0 + q * 8);
    }
#pragma unroll
    for (int mi = 0; mi < 4; ++mi)
#pragma unroll
      for (int ni = 0; ni < 2; ++ni)
        acc[mi][ni] = __builtin_amdgcn_mfma_f32_16x16x32_bf16(a[mi], b[ni], acc[mi][ni], 0, 0, 0);
  }
#pragma unroll
  for (int mi = 0; mi < 4; ++mi) {
    int ch = w * 64 + 16 * mi + 4 * q;
    float4 bv = addb ? *(const float4*)(be1 + ch) : (float4){0.f, 0.f, 0.f, 0.f};
#pragma unroll
    for (int ni = 0; ni < 2; ++ni) {
      int m = m0 + 16 * ni + r;
      if (m < N_NODES) {
        uint2 o;
        o.x = pk_bf16(acc[mi][ni][0] + bv.x, acc[mi][ni][1] + bv.y);
        o.y = pk_bf16(acc[mi][ni][2] + bv.z, acc[mi][ni][3] + bv.w);
        *(uint2*)(OUT + (size_t)m * 256 + ch) = o;
      }
    }
  }
}

// ---- edge kernel: 64 sorted edges/block, transposed GEMMs, fused coord-MLP epilogue,
// bf16 P/Q gathers (round-3 layout; f32 P/Q regressed via FETCH blowup), rcp-silu.
__global__ __launch_bounds__(256, 4) void edge_kernel(
    const float* __restrict__ coord, const int* __restrict__ rs, const int* __restrict__ cs,
    const float* __restrict__ We1,
    const float* __restrict__ be2, const float* __restrict__ bc1,
    const float* __restrict__ Wc2, const float* __restrict__ bc2,
    const bf16* __restrict__ P, const bf16* __restrict__ Q,
    const bf16* __restrict__ We2T, const bf16* __restrict__ Wc1T,
    float* __restrict__ agg_h, float* __restrict__ agg_c) {
  __shared__ __align__(16) bf16 buf[64 * KPAD];
  __shared__ int s_row[64], s_col[64];
  __shared__ float s_rad[64], s_cd[64][3], s_part[64][4], s_scal[64];
  __shared__ int s_rs[65];
  __shared__ int s_nrun;

  int tid = threadIdx.x;
  int e0 = blockIdx.x * 64;
  int w = tid >> 6, lane = tid & 63, r = lane & 15, q = lane >> 4;

  if (tid < 64) {
    int e = e0 + tid;
    int ri = rs[e], ci = cs[e];
    s_row[tid] = ri; s_col[tid] = ci;
    float dx = coord[3 * ri + 0] - coord[3 * ci + 0];
    float dy = coord[3 * ri + 1] - coord[3 * ci + 1];
    float dz = coord[3 * ri + 2] - coord[3 * ci + 2];
    s_cd[tid][0] = dx; s_cd[tid][1] = dy; s_cd[tid][2] = dz;
    s_rad[tid] = dx * dx + dy * dy + dz * dz;
  }
  __syncthreads();

  // wave 0: run boundaries of sorted rows (avg 2-3 runs/block)
  if (tid < 64) {
    bool bnd = (tid == 0) || (s_row[tid] != s_row[tid - 1]);
    unsigned long long m = __ballot(bnd);
    int rank = __popcll(m & ((1ull << tid) - 1ull));
    if (bnd) s_rs[rank] = tid;
    if (tid == 0) { int R = __popcll(m); s_nrun = R; s_rs[R] = 64; }
  }

  // e1 = silu(P[row] + Q[col] + radial*We1[512]) -> buf (be1 pre-folded into P)
  {
    int off = (tid & 31) * 8;
    int esub = tid >> 5;
    float4 wa = *(const float4*)(We1 + 512 * 256 + off);
    float4 wb = *(const float4*)(We1 + 512 * 256 + off + 4);
#pragma unroll
    for (int p = 0; p < 8; ++p) {
      int e = p * 8 + esub;
      int ri = s_row[e], ci = s_col[e];
      bf16x8 pv = *(const bf16x8*)(P + (size_t)ri * 256 + off);
      bf16x8 qv = *(const bf16x8*)(Q + (size_t)ci * 256 + off);
      float rad = s_rad[e];
      float f0 = silu_f((float)pv[0] + (float)qv[0] + rad * wa.x);
      float f1 = silu_f((float)pv[1] + (float)qv[1] + rad * wa.y);
      float f2 = silu_f((float)pv[2] + (float)qv[2] + rad * wa.z);
      float f3 = silu_f((float)pv[3] + (float)qv[3] + rad * wa.w);
      float f4 = silu_f((float)pv[4] + (float)qv[4] + rad * wb.x);
      float f5 = silu_f((float)pv[5] + (float)qv[5] + rad * wb.y);
      float f6 = silu_f((float)pv[6] + (float)qv[6] + rad * wb.z);
      float f7 = silu_f((float)pv[7] + (float)qv[7] + rad * wb.w);
      uint4 o;
      o.x = pk_bf16(f0, f1); o.y = pk_bf16(f2, f3);
      o.z = pk_bf16(f4, f5); o.w = pk_bf16(f6, f7);
      *(uint4*)(buf + e * KPAD + off) = o;
    }
  }
  __syncthreads();

  // GEMM1-T: edge_feat: acc rows = We2 out-channels, cols = edges
  {
    f32x4 acc[4][4];
#pragma unroll
    for (int mi = 0; mi < 4; ++mi)
#pragma unroll
      for (int ni = 0; ni < 4; ++ni) acc[mi][ni] = (f32x4){0.f, 0.f, 0.f, 0.f};
    mfmaT_k256(We2T, 256, 0, buf, w, r, q, acc);
    __syncthreads();   // all reads of e1 done before overwrite
#pragma unroll
    for (int mi = 0; mi < 4; ++mi) {
      int ch = w * 64 + 16 * mi + 4 * q;
      float4 bv = *(const float4*)(be2 + ch);
#pragma unroll
      for (int ni = 0; ni < 4; ++ni) {
        int edge = 16 * ni + r;
        float f0 = silu_f(acc[mi][ni][0] + bv.x);
        float f1 = silu_f(acc[mi][ni][1] + bv.y);
        float f2 = silu_f(acc[mi][ni][2] + bv.z);
        float f3 = silu_f(acc[mi][ni][3] + bv.w);
        uint2 o; o.x = pk_bf16(f0, f1); o.y = pk_bf16(f2, f3);
        *(uint2*)(buf + edge * KPAD + ch) = o;  // buf[edge][ch], b64 write
      }
    }
  }
  __syncthreads();

  // GEMM2-T k-loop (reads edge_feat) ...
  f32x4 acc2[4][4];
#pragma unroll
  for (int mi = 0; mi < 4; ++mi)
#pragma unroll
    for (int ni = 0; ni < 4; ++ni) acc2[mi][ni] = (f32x4){0.f, 0.f, 0.f, 0.f};
  mfmaT_k256(Wc1T, 256, 0, buf, w, r, q, acc2);

  // ... interleaved with run-based agg_h column sums (also reads edge_feat)
  {
    int R = s_nrun;
    for (int rr = 0; rr < R; ++rr) {
      int st = s_rs[rr], en = s_rs[rr + 1];
      float s = 0.f;
      for (int e = st; e < en; ++e) s += (float)buf[e * KPAD + tid];
      atomicAdd(&agg_h[(size_t)s_row[st] * 256 + tid], s);
    }
  }

  // GEMM2 fused epilogue: scalar partials p[edge] = sum_ch silu(c1)*Wc2[ch],
  // computed straight from acc2 registers (c1 never written to LDS).
  {
    float p[4] = {0.f, 0.f, 0.f, 0.f};
#pragma unroll
    for (int mi = 0; mi < 4; ++mi) {
      int ch = w * 64 + 16 * mi + 4 * q;
      float4 bv = *(const float4*)(bc1 + ch);
      float4 wv = *(const float4*)(Wc2 + ch);
#pragma unroll
      for (int ni = 0; ni < 4; ++ni) {
        p[ni] += silu_f(acc2[mi][ni][0] + bv.x) * wv.x
               + silu_f(acc2[mi][ni][1] + bv.y) * wv.y
               + silu_f(acc2[mi][ni][2] + bv.z) * wv.z
               + silu_f(acc2[mi][ni][3] + bv.w) * wv.w;
      }
    }
    // reduce over the 4 q-lane-groups (lanes r, r+16, r+32, r+48 hold the same edge)
#pragma unroll
    for (int ni = 0; ni < 4; ++ni) {
      float v = p[ni];
      v += __shfl_xor(v, 16, 64);
      v += __shfl_xor(v, 32, 64);
      if (q == 0) s_part[16 * ni + r][w] = v;
    }
  }
  __syncthreads();   // s_part ready (agg_h atomics need no barrier)

  if (tid < 64)
    s_scal[tid] = s_part[tid][0] + s_part[tid][1] + s_part[tid][2] + s_part[tid][3] + bc2[0];
  __syncthreads();

  // coord aggregation: run-based, one lane per xyz component
  if (tid < 3) {
    int R = s_nrun;
    for (int rr = 0; rr < R; ++rr) {
      int st = s_rs[rr], en = s_rs[rr + 1];
      float s = 0.f;
      for (int e = st; e < en; ++e) s += s_cd[e][tid] * s_scal[e];
      atomicAdd(&agg_c[3 * s_row[st] + tid], s);
    }
  }
}

// ---- node kernel (fused post): coord_out + agg->bf16 inline + 2-layer node MLP.
// 32-node tiles (313 blocks) to halve single-block critical path (~1 block/CU launch).
__global__ __launch_bounds__(256, 2) void node_kernel(
    const bf16* __restrict__ Hb, const float* __restrict__ agg_h,
    const int* __restrict__ hist, const float* __restrict__ coord, const float* __restrict__ agg_c,
    const bf16* __restrict__ Wn1T, const bf16* __restrict__ Wn2T,
    const float* __restrict__ bn1, const float* __restrict__ bn2,
    float* __restrict__ h_out, float* __restrict__ coord_out) {
  __shared__ __align__(16) bf16 buf[32 * KPAD];
  int tid = threadIdx.x, w = tid >> 6, lane = tid & 63, r = lane & 15, q = lane >> 4;
  int m0 = blockIdx.x * 32;

  // coord_out
  if (tid < 32) {
    int m = m0 + tid;
    if (m < N_NODES) {
      float c = (float)hist[m]; if (c < 1.f) c = 1.f;
      coord_out[3 * m + 0] = coord[3 * m + 0] + agg_c[3 * m + 0] / c;
      coord_out[3 * m + 1] = coord[3 * m + 1] + agg_c[3 * m + 1] / c;
      coord_out[3 * m + 2] = coord[3 * m + 2] + agg_c[3 * m + 2] / c;
    }
  }

  // layer1: rows = hidden channels, cols = nodes (32)
  f32x4 acc[4][2];
#pragma unroll
  for (int mi = 0; mi < 4; ++mi)
#pragma unroll
    for (int ni = 0; ni < 2; ++ni) acc[mi][ni] = (f32x4){0.f, 0.f, 0.f, 0.f};
  // part A: h (k 0..255), B from Hb global
  for (int k0 = 0; k0 < 256; k0 += 32) {
    bf16x8 a[4], b[2];
#pragma unroll
    for (int mi = 0; mi < 4; ++mi)
      a[mi] = *(const bf16x8*)(Wn1T + (size_t)(w * 64 + 16 * mi + r) * 512 + k0 + q * 8);
#pragma unroll
    for (int ni = 0; ni < 2; ++ni) {
      int m = m0 + 16 * ni + r; if (m > N_NODES - 1) m = N_NODES - 1;
      b[ni] = *(const bf16x8*)(Hb + (size_t)m * 256 + k0 + q * 8);
    }
#pragma unroll
    for (int mi = 0; mi < 4; ++mi)
#pragma unroll
      for (int ni = 0; ni < 2; ++ni)
        acc[mi][ni] = __builtin_amdgcn_mfma_f32_16x16x32_bf16(a[mi], b[ni], acc[mi][ni], 0, 0, 0);
  }
  // part B: agg_h f32 -> bf16 on the fly (k 256..511)
  for (int k0 = 0; k0 < 256; k0 += 32) {
    bf16x8 a[4], b[2];
#pragma unroll
    for (int mi = 0; mi < 4; ++mi)
      a[mi] = *(const bf16x8*)(Wn1T + (size_t)(w * 64 + 16 * mi + r) * 512 + 256 + k0 + q * 8);
#pragma unroll
    for (int ni = 0; ni < 2; ++ni) {
      int m = m0 + 16 * ni + r; if (m > N_NODES - 1) m = N_NODES - 1;
      const float* ap = agg_h + (size_t)m * 256 + k0 + q * 8;
      float4 u = *(const float4*)ap;
      float4 v = *(const float4*)(ap + 4);
      uint4 o;
      o.x = pk_bf16(u.x, u.y); o.y = pk_bf16(u.z, u.w);
      o.z = pk_bf16(v.x, v.y); o.w = pk_bf16(v.z, v.w);
      b[ni] = *(const bf16x8*)&o;
    }
#pragma unroll
    for (int mi = 0; mi < 4; ++mi)
#pragma unroll
      for (int ni = 0; ni < 2; ++ni)
        acc[mi][ni] = __builtin_amdgcn_mfma_f32_16x16x32_bf16(a[mi], b[ni], acc[mi][ni], 0, 0, 0);
  }
  __syncthreads();
  // epilogue -> buf[node_local][hidden], b64 writes
#pragma unroll
  for (int mi = 0; mi < 4; ++mi) {
    int ch = w * 64 + 16 * mi + 4 * q;
    float4 bv = *(const float4*)(bn1 + ch);
#pragma unroll
    for (int ni = 0; ni < 2; ++ni) {
      int lm = 16 * ni + r;
      float f0 = silu_f(acc[mi][ni][0] + bv.x);
      float f1 = silu_f(acc[mi][ni][1] + bv.y);
      float f2 = silu_f(acc[mi][ni][2] + bv.z);
      float f3 = silu_f(acc[mi][ni][3] + bv.w);
      uint2 o; o.x = pk_bf16(f0, f1); o.y = pk_bf16(f2, f3);
      *(uint2*)(buf + lm * KPAD + ch) = o;
    }
  }
  __syncthreads();
  // layer2 -> h_out (float4 stores)
  f32x4 acc2[4][2];
#pragma unroll
  for (int mi = 0; mi < 4; ++mi)
#pragma unroll
    for (int ni = 0; ni < 2; ++ni) acc2[mi][ni] = (f32x4){0.f, 0.f, 0.f, 0.f};
  mfmaT_k256_b2(Wn2T, 256, 0, buf, w, r, q, acc2);
#pragma unroll
  for (int mi = 0; mi < 4; ++mi) {
    int ch = w * 64 + 16 * mi + 4 * q;
    float4 bv = *(const float4*)(bn2 + ch);
#pragma unroll
    for (int ni = 0; ni < 2; ++ni) {
      int m = m0 + 16 * ni + r;
      if (m < N_NODES) {
        float4 o;
        o.x = acc2[mi][ni][0] + bv.x;
        o.y = acc2[mi][ni][1] + bv.y;
        o.z = acc2[mi][ni][2] + bv.z;
        o.w = acc2[mi][ni][3] + bv.w;
        *(float4*)(h_out + (size_t)m * 256 + ch) = o;
      }
    }
  }
}

extern "C" void kernel_launch(void* const* d_in, const int* in_sizes, int n_in,
                              void* d_out, int out_size, void* d_ws, size_t ws_size,
                              hipStream_t stream) {
  const float* h     = (const float*)d_in[0];
  const float* coord = (const float*)d_in[1];
  const int*   eidx  = (const int*)d_in[2];
  const float* We1 = (const float*)d_in[3];
  const float* be1 = (const float*)d_in[4];
  const float* We2 = (const float*)d_in[5];
  const float* be2 = (const float*)d_in[6];
  const float* Wn1 = (const float*)d_in[7];
  const float* bn1 = (const float*)d_in[8];
  const float* Wn2 = (const float*)d_in[9];
  const float* bn2 = (const float*)d_in[10];
  const float* Wc1 = (const float*)d_in[11];
  const float* bc1 = (const float*)d_in[12];
  const float* Wc2 = (const float*)d_in[13];
  const float* bc2 = (const float*)d_in[14];

  char* ws = (char*)d_ws;
  float* agg_h = (float*)(ws + 0);          // 10,240,000
  float* agg_c = (float*)(ws + 10240000);   //    120,000
  int*   hist  = (int*)  (ws + 10360000);   //     40,000
  int*   base  = (int*)  (ws + 10400000);   //     40,000
  int*   cursor= (int*)  (ws + 10440000);   //     40,000
  int*   rs    = (int*)  (ws + 10480000);   //  1,280,000
  int*   cs    = (int*)  (ws + 11760000);   //  1,280,000
  bf16* Hb   = (bf16*)(ws + 13040000);      //  5,120,000
  bf16* P    = (bf16*)(ws + 18160000);      //  5,120,000
  bf16* Q    = (bf16*)(ws + 23280000);      //  5,120,000
  bf16* We1T = (bf16*)(ws + 28400000);      //    262,144
  bf16* Wn1T = (bf16*)(ws + 28662144);      //    262,144
  bf16* We2T = (bf16*)(ws + 28924288);      //    131,072
  bf16* Wn2T = (bf16*)(ws + 29055360);      //    131,072
  bf16* Wc1T = (bf16*)(ws + 29186432);      //    131,072

  float* h_out = (float*)d_out;
  float* coord_out = h_out + (size_t)N_NODES * 256;

  hipMemsetAsync(ws, 0, 10400000, stream);  // agg_h + agg_c + hist
  prep_kernel<<<13042, 256, 0, stream>>>(h, We1, We2, Wn1, Wn2, Wc1, eidx,
                                         Hb, We1T, Wn1T, We2T, Wn2T, Wc1T, hist);
  scan_kernel<<<1, 256, 0, stream>>>(hist, base, cursor);
  scatter_kernel<<<1250, 256, 0, stream>>>(eidx, cursor, rs, cs);
  gemm_pq<<<dim3(313, 2), 256, 0, stream>>>(Hb, We1T, be1, P, Q);
  edge_kernel<<<5000, 256, 0, stream>>>(coord, rs, cs, We1, be2, bc1, Wc2, bc2,
                                        P, Q, We2T, Wc1T, agg_h, agg_c);
  node_kernel<<<313, 256, 0, stream>>>(Hb, agg_h, hist, coord, agg_c,
                                       Wn1T, Wn2T, bn1, bn2, h_out, coord_out);
}

// Round 6
// 408.981 us; speedup vs baseline: 1.1030x; 1.0305x over previous
//
#include <hip/hip_runtime.h>
#include <hip/hip_bf16.h>

typedef __bf16 bf16;
typedef __attribute__((ext_vector_type(8))) __bf16 bf16x8;
typedef __attribute__((ext_vector_type(4))) float f32x4;

static_assert(sizeof(bf16x8) == 16, "bf16x8 must be 16B");

constexpr int N_NODES = 10000;
constexpr int N_EDGES = 320000;
constexpr int KPAD    = 264;   // LDS row stride (bf16): 528B/row -> 2-way bank aliasing (free per m136)

// single-instruction reciprocal (~1 ulp; exact enough under bf16 rounding).
__device__ __forceinline__ float rcp_f(float x) {
  float r; asm("v_rcp_f32 %0, %1" : "=v"(r) : "v"(x)); return r;
}
// silu via rcp: 5 VALU insts vs ~11 for IEEE divide sequence. rcp(inf)=0 -> silu(-big)=0 correct.
__device__ __forceinline__ float silu_f(float x) { return x * rcp_f(1.0f + __expf(-x)); }

// pack two f32 -> (bf16(lo), bf16(hi)) in one u32 via HW packed convert (RNE).
__device__ __forceinline__ unsigned pk_bf16(float lo, float hi) {
  unsigned r;
  asm("v_cvt_pk_bf16_f32 %0, %1, %2" : "=v"(r) : "v"(lo), "v"(hi));
  return r;
}

// ---- transposed-output MFMA: acc[mi][ni] = WT-rows x rows-of-Albs (4x4 tile, 64 cols).
// D row(q*4+reg) = out channel (w*64+16*mi+4q+rg), D col(lane&15) = col-row (16*ni+r).
__device__ __forceinline__ void mfmaT_k256(const bf16* __restrict__ WT, int wstride, int koff,
                                           const bf16* Albs, int w, int r, int q, f32x4 acc[4][4]) {
  for (int k0 = 0; k0 < 256; k0 += 32) {
    bf16x8 a[4], b[4];
#pragma unroll
    for (int mi = 0; mi < 4; ++mi)
      a[mi] = *(const bf16x8*)(WT + (size_t)(w * 64 + 16 * mi + r) * wstride + koff + k0 + q * 8);
#pragma unroll
    for (int ni = 0; ni < 4; ++ni)
      b[ni] = *(const bf16x8*)(Albs + (16 * ni + r) * KPAD + k0 + q * 8);
#pragma unroll
    for (int mi = 0; mi < 4; ++mi)
#pragma unroll
      for (int ni = 0; ni < 4; ++ni)
        acc[mi][ni] = __builtin_amdgcn_mfma_f32_16x16x32_bf16(a[mi], b[ni], acc[mi][ni], 0, 0, 0);
  }
}

// ---- 4x1 variant (16-col tiles: gemm_pq / node splits for TLP)
__device__ __forceinline__ void mfmaT_k256_b1(const bf16* __restrict__ WT, int wstride, int koff,
                                              const bf16* Albs, int w, int r, int q, f32x4 acc[4]) {
  for (int k0 = 0; k0 < 256; k0 += 32) {
    bf16x8 a[4], b;
    b = *(const bf16x8*)(Albs + r * KPAD + k0 + q * 8);
#pragma unroll
    for (int mi = 0; mi < 4; ++mi)
      a[mi] = *(const bf16x8*)(WT + (size_t)(w * 64 + 16 * mi + r) * wstride + koff + k0 + q * 8);
#pragma unroll
    for (int mi = 0; mi < 4; ++mi)
      acc[mi] = __builtin_amdgcn_mfma_f32_16x16x32_bf16(a[mi], b, acc[mi], 0, 0, 0);
  }
}

// ---- prep: h -> bf16; weight transposes with COALESCED bf16x8 output; hist; agg zeroing.
// Transpose writes were 2B stride-512 scatter (64x write amplification) -> now 16B contiguous
// per lane (reads become stride-1KB 4B scatter, absorbed by L2 since weights are L2-resident).
__device__ __forceinline__ void transpose512(const float* __restrict__ W, bf16* __restrict__ WT,
                                             int local, int tid) {
  int tg = local * 256 + tid;        // 0..16383 covers 256x512
  int j = tg >> 6, k0 = (tg & 63) * 8;
  bf16x8 v;
#pragma unroll
  for (int i = 0; i < 8; ++i) v[i] = (bf16)W[(size_t)(k0 + i) * 256 + j];
  *(bf16x8*)(WT + (size_t)j * 512 + k0) = v;
}
__device__ __forceinline__ void transpose256(const float* __restrict__ W, bf16* __restrict__ WT,
                                             int local, int tid) {
  int tg = local * 256 + tid;        // 0..8191 covers 256x256
  int j = tg >> 5, k0 = (tg & 31) * 8;
  bf16x8 v;
#pragma unroll
  for (int i = 0; i < 8; ++i) v[i] = (bf16)W[(size_t)(k0 + i) * 256 + j];
  *(bf16x8*)(WT + (size_t)j * 256 + k0) = v;
}

__global__ __launch_bounds__(256) void prep_kernel(
    const float* __restrict__ h, const float* __restrict__ We1, const float* __restrict__ We2,
    const float* __restrict__ Wn1, const float* __restrict__ Wn2, const float* __restrict__ Wc1,
    const int* __restrict__ eidx,
    bf16* __restrict__ Hb, bf16* __restrict__ We1T, bf16* __restrict__ Wn1T,
    bf16* __restrict__ We2T, bf16* __restrict__ Wn2T, bf16* __restrict__ Wc1T,
    int* __restrict__ hist, float4* __restrict__ zero_base) {
  int bid = blockIdx.x, tid = threadIdx.x;
  if (bid < 10000) { int i = bid * 256 + tid; Hb[i] = (bf16)h[i]; return; }
  if (bid < 10224) {               // 224 transpose blocks
    int wb = bid - 10000;
    if (wb < 64)       transpose512(We1, We1T, wb, tid);
    else if (wb < 128) transpose512(Wn1, Wn1T, wb - 64, tid);
    else if (wb < 160) transpose256(We2, We2T, wb - 128, tid);
    else if (wb < 192) transpose256(Wn2, Wn2T, wb - 160, tid);
    else               transpose256(Wc1, Wc1T, wb - 192, tid);
    return;
  }
  if (bid < 11474) {               // 1250 hist blocks (fire-and-forget atomics)
    int e = (bid - 11474 + 1250) * 256 + tid - 1250 * 256;  // = (bid-10224)*256+tid
    e = (bid - 10224) * 256 + tid;
    if (e < N_EDGES) atomicAdd(&hist[eidx[e]], 1);
    return;
  }
  // 2540 zero blocks: agg_h + agg_c (10,360,000 B = 647,500 float4). hist zeroed by host memset
  // (zeroing it here would race the hist atomics above).
  int z = (bid - 11474) * 256 + tid;
  if (z < 647500) zero_base[z] = (float4){0.f, 0.f, 0.f, 0.f};
}

// ---- scan: LDS-staged (coalesced global loads/stores; per-thread work on LDS)
__global__ __launch_bounds__(256) void scan_kernel(const int* __restrict__ hist,
                                                   int* __restrict__ base, int* __restrict__ cursor) {
  __shared__ int sh[10000];
  __shared__ int partial[256];
  int t = threadIdx.x;
  for (int i = 0; i < 40; ++i) { int idx = i * 256 + t; if (idx < N_NODES) sh[idx] = hist[idx]; }
  __syncthreads();
  int s = 0;
  for (int i = 0; i < 40; ++i) { int idx = t * 40 + i; if (idx < N_NODES) s += sh[idx]; }
  partial[t] = s;
  __syncthreads();
  for (int d = 1; d < 256; d <<= 1) {
    int v = (t >= d) ? partial[t - d] : 0;
    __syncthreads();
    partial[t] += v;
    __syncthreads();
  }
  int run = partial[t] - s;  // exclusive
  for (int i = 0; i < 40; ++i) {
    int idx = t * 40 + i;
    if (idx < N_NODES) { int hv = sh[idx]; sh[idx] = run; run += hv; }
  }
  __syncthreads();
  for (int i = 0; i < 40; ++i) {
    int idx = i * 256 + t;
    if (idx < N_NODES) { int v = sh[idx]; base[idx] = v; cursor[idx] = v; }
  }
}

// ---- scatter: packed (r,c) 8B stores (halves scattered-store transactions)
__global__ __launch_bounds__(256) void scatter_kernel(const int* __restrict__ eidx, int* __restrict__ cursor,
                                                      int2* __restrict__ rc) {
  int e = blockIdx.x * 256 + threadIdx.x;
  if (e < N_EDGES) {
    int r = eidx[e], c = eidx[N_EDGES + e];
    int p = atomicAdd(&cursor[r], 1);
    rc[p] = (int2){r, c};
  }
}

// ---- P/Q GEMM: 16-node tiles (grid 625x2 = 1250 blocks, ~5 blocks/CU) for latency hiding.
__global__ __launch_bounds__(256, 2) void gemm_pq(const bf16* __restrict__ Hb,
                                                  const bf16* __restrict__ We1T,
                                                  const float* __restrict__ be1,
                                                  bf16* __restrict__ P, bf16* __restrict__ Q) {
  int tid = threadIdx.x, w = tid >> 6, lane = tid & 63, r = lane & 15, q = lane >> 4;
  int m0 = blockIdx.x * 16;
  int koff = blockIdx.y ? 256 : 0;
  bf16* OUT = blockIdx.y ? Q : P;
  bool addb = (blockIdx.y == 0);
  f32x4 acc[4];
#pragma unroll
  for (int mi = 0; mi < 4; ++mi) acc[mi] = (f32x4){0.f, 0.f, 0.f, 0.f};
  int m = m0 + r;  // 624*16+15 = 9999 max: always in range

  for (int k0 = 0; k0 < 256; k0 += 32) {
    bf16x8 a[4], b;
    b = *(const bf16x8*)(Hb + (size_t)m * 256 + k0 + q * 8);
#pragma unroll
    for (int mi = 0; mi < 4; ++mi)
      a[mi] = *(const bf16x8*)(We1T + (size_t)(w * 64 + 16 * mi + r) * 512 + koff + k0 + q * 8);
#pragma unroll
    for (int mi = 0; mi < 4; ++mi)
      acc[mi] = __builtin_amdgcn_mfma_f32_16x16x32_bf16(a[mi], b, acc[mi], 0, 0, 0);
  }
#pragma unroll
  for (int mi = 0; mi < 4; ++mi) {
    int ch = w * 64 + 16 * mi + 4 * q;
    float4 bv = addb ? *(const float4*)(be1 + ch) : (float4){0.f, 0.f, 0.f, 0.f};
    uint2 o;
    o.x = pk_bf16(acc[mi][0] + bv.x, acc[mi][1] + bv.y);
    o.y = pk_bf16(acc[mi][2] + bv.z, acc[mi][3] + bv.w);
    *(uint2*)(OUT + (size_t)m * 256 + ch) = o;
  }
}

// ---- edge kernel: 64 sorted edges/block, transposed GEMMs, fused coord-MLP epilogue,
// bf16 P/Q gathers, rcp-silu, packed rc edge list. (UNCHANGED vs round 5 otherwise.)
__global__ __launch_bounds__(256, 4) void edge_kernel(
    const float* __restrict__ coord, const int2* __restrict__ rc,
    const float* __restrict__ We1,
    const float* __restrict__ be2, const float* __restrict__ bc1,
    const float* __restrict__ Wc2, const float* __restrict__ bc2,
    const bf16* __restrict__ P, const bf16* __restrict__ Q,
    const bf16* __restrict__ We2T, const bf16* __restrict__ Wc1T,
    float* __restrict__ agg_h, float* __restrict__ agg_c) {
  __shared__ __align__(16) bf16 buf[64 * KPAD];
  __shared__ int s_row[64], s_col[64];
  __shared__ float s_rad[64], s_cd[64][3], s_part[64][4], s_scal[64];
  __shared__ int s_rs[65];
  __shared__ int s_nrun;

  int tid = threadIdx.x;
  int e0 = blockIdx.x * 64;
  int w = tid >> 6, lane = tid & 63, r = lane & 15, q = lane >> 4;

  if (tid < 64) {
    int2 v = rc[e0 + tid];
    int ri = v.x, ci = v.y;
    s_row[tid] = ri; s_col[tid] = ci;
    float dx = coord[3 * ri + 0] - coord[3 * ci + 0];
    float dy = coord[3 * ri + 1] - coord[3 * ci + 1];
    float dz = coord[3 * ri + 2] - coord[3 * ci + 2];
    s_cd[tid][0] = dx; s_cd[tid][1] = dy; s_cd[tid][2] = dz;
    s_rad[tid] = dx * dx + dy * dy + dz * dz;
  }
  __syncthreads();

  // wave 0: run boundaries of sorted rows (avg 2-3 runs/block)
  if (tid < 64) {
    bool bnd = (tid == 0) || (s_row[tid] != s_row[tid - 1]);
    unsigned long long m = __ballot(bnd);
    int rank = __popcll(m & ((1ull << tid) - 1ull));
    if (bnd) s_rs[rank] = tid;
    if (tid == 0) { int R = __popcll(m); s_nrun = R; s_rs[R] = 64; }
  }

  // e1 = silu(P[row] + Q[col] + radial*We1[512]) -> buf (be1 pre-folded into P)
  {
    int off = (tid & 31) * 8;
    int esub = tid >> 5;
    float4 wa = *(const float4*)(We1 + 512 * 256 + off);
    float4 wb = *(const float4*)(We1 + 512 * 256 + off + 4);
#pragma unroll
    for (int p = 0; p < 8; ++p) {
      int e = p * 8 + esub;
      int ri = s_row[e], ci = s_col[e];
      bf16x8 pv = *(const bf16x8*)(P + (size_t)ri * 256 + off);
      bf16x8 qv = *(const bf16x8*)(Q + (size_t)ci * 256 + off);
      float rad = s_rad[e];
      float f0 = silu_f((float)pv[0] + (float)qv[0] + rad * wa.x);
      float f1 = silu_f((float)pv[1] + (float)qv[1] + rad * wa.y);
      float f2 = silu_f((float)pv[2] + (float)qv[2] + rad * wa.z);
      float f3 = silu_f((float)pv[3] + (float)qv[3] + rad * wa.w);
      float f4 = silu_f((float)pv[4] + (float)qv[4] + rad * wb.x);
      float f5 = silu_f((float)pv[5] + (float)qv[5] + rad * wb.y);
      float f6 = silu_f((float)pv[6] + (float)qv[6] + rad * wb.z);
      float f7 = silu_f((float)pv[7] + (float)qv[7] + rad * wb.w);
      uint4 o;
      o.x = pk_bf16(f0, f1); o.y = pk_bf16(f2, f3);
      o.z = pk_bf16(f4, f5); o.w = pk_bf16(f6, f7);
      *(uint4*)(buf + e * KPAD + off) = o;
    }
  }
  __syncthreads();

  // GEMM1-T: edge_feat: acc rows = We2 out-channels, cols = edges
  {
    f32x4 acc[4][4];
#pragma unroll
    for (int mi = 0; mi < 4; ++mi)
#pragma unroll
      for (int ni = 0; ni < 4; ++ni) acc[mi][ni] = (f32x4){0.f, 0.f, 0.f, 0.f};
    mfmaT_k256(We2T, 256, 0, buf, w, r, q, acc);
    __syncthreads();   // all reads of e1 done before overwrite
#pragma unroll
    for (int mi = 0; mi < 4; ++mi) {
      int ch = w * 64 + 16 * mi + 4 * q;
      float4 bv = *(const float4*)(be2 + ch);
#pragma unroll
      for (int ni = 0; ni < 4; ++ni) {
        int edge = 16 * ni + r;
        float f0 = silu_f(acc[mi][ni][0] + bv.x);
        float f1 = silu_f(acc[mi][ni][1] + bv.y);
        float f2 = silu_f(acc[mi][ni][2] + bv.z);
        float f3 = silu_f(acc[mi][ni][3] + bv.w);
        uint2 o; o.x = pk_bf16(f0, f1); o.y = pk_bf16(f2, f3);
        *(uint2*)(buf + edge * KPAD + ch) = o;  // buf[edge][ch], b64 write
      }
    }
  }
  __syncthreads();

  // GEMM2-T k-loop (reads edge_feat) ...
  f32x4 acc2[4][4];
#pragma unroll
  for (int mi = 0; mi < 4; ++mi)
#pragma unroll
    for (int ni = 0; ni < 4; ++ni) acc2[mi][ni] = (f32x4){0.f, 0.f, 0.f, 0.f};
  mfmaT_k256(Wc1T, 256, 0, buf, w, r, q, acc2);

  // ... interleaved with run-based agg_h column sums (also reads edge_feat)
  {
    int R = s_nrun;
    for (int rr = 0; rr < R; ++rr) {
      int st = s_rs[rr], en = s_rs[rr + 1];
      float s = 0.f;
      for (int e = st; e < en; ++e) s += (float)buf[e * KPAD + tid];
      atomicAdd(&agg_h[(size_t)s_row[st] * 256 + tid], s);
    }
  }

  // GEMM2 fused epilogue: scalar partials p[edge] = sum_ch silu(c1)*Wc2[ch],
  // computed straight from acc2 registers (c1 never written to LDS).
  {
    float p[4] = {0.f, 0.f, 0.f, 0.f};
#pragma unroll
    for (int mi = 0; mi < 4; ++mi) {
      int ch = w * 64 + 16 * mi + 4 * q;
      float4 bv = *(const float4*)(bc1 + ch);
      float4 wv = *(const float4*)(Wc2 + ch);
#pragma unroll
      for (int ni = 0; ni < 4; ++ni) {
        p[ni] += silu_f(acc2[mi][ni][0] + bv.x) * wv.x
               + silu_f(acc2[mi][ni][1] + bv.y) * wv.y
               + silu_f(acc2[mi][ni][2] + bv.z) * wv.z
               + silu_f(acc2[mi][ni][3] + bv.w) * wv.w;
      }
    }
    // reduce over the 4 q-lane-groups (lanes r, r+16, r+32, r+48 hold the same edge)
#pragma unroll
    for (int ni = 0; ni < 4; ++ni) {
      float v = p[ni];
      v += __shfl_xor(v, 16, 64);
      v += __shfl_xor(v, 32, 64);
      if (q == 0) s_part[16 * ni + r][w] = v;
    }
  }
  __syncthreads();   // s_part ready (agg_h atomics need no barrier)

  if (tid < 64)
    s_scal[tid] = s_part[tid][0] + s_part[tid][1] + s_part[tid][2] + s_part[tid][3] + bc2[0];
  __syncthreads();

  // coord aggregation: run-based, one lane per xyz component
  if (tid < 3) {
    int R = s_nrun;
    for (int rr = 0; rr < R; ++rr) {
      int st = s_rs[rr], en = s_rs[rr + 1];
      float s = 0.f;
      for (int e = st; e < en; ++e) s += s_cd[e][tid] * s_scal[e];
      atomicAdd(&agg_c[3 * s_row[st] + tid], s);
    }
  }
}

// ---- node kernel: 16-node tiles (625 blocks, ~2.4 blocks/CU) for TLP; fused post.
__global__ __launch_bounds__(256, 2) void node_kernel(
    const bf16* __restrict__ Hb, const float* __restrict__ agg_h,
    const int* __restrict__ hist, const float* __restrict__ coord, const float* __restrict__ agg_c,
    const bf16* __restrict__ Wn1T, const bf16* __restrict__ Wn2T,
    const float* __restrict__ bn1, const float* __restrict__ bn2,
    float* __restrict__ h_out, float* __restrict__ coord_out) {
  __shared__ __align__(16) bf16 buf[16 * KPAD];
  int tid = threadIdx.x, w = tid >> 6, lane = tid & 63, r = lane & 15, q = lane >> 4;
  int m0 = blockIdx.x * 16;
  int m = m0 + r;  // 624*16+15 = 9999 max: in range

  // coord_out
  if (tid < 16) {
    int mm = m0 + tid;
    float c = (float)hist[mm]; if (c < 1.f) c = 1.f;
    coord_out[3 * mm + 0] = coord[3 * mm + 0] + agg_c[3 * mm + 0] / c;
    coord_out[3 * mm + 1] = coord[3 * mm + 1] + agg_c[3 * mm + 1] / c;
    coord_out[3 * mm + 2] = coord[3 * mm + 2] + agg_c[3 * mm + 2] / c;
  }

  // layer1: rows = hidden channels, cols = 16 nodes
  f32x4 acc[4];
#pragma unroll
  for (int mi = 0; mi < 4; ++mi) acc[mi] = (f32x4){0.f, 0.f, 0.f, 0.f};
  // part A: h (k 0..255), B from Hb global
  for (int k0 = 0; k0 < 256; k0 += 32) {
    bf16x8 a[4], b;
    b = *(const bf16x8*)(Hb + (size_t)m * 256 + k0 + q * 8);
#pragma unroll
    for (int mi = 0; mi < 4; ++mi)
      a[mi] = *(const bf16x8*)(Wn1T + (size_t)(w * 64 + 16 * mi + r) * 512 + k0 + q * 8);
#pragma unroll
    for (int mi = 0; mi < 4; ++mi)
      acc[mi] = __builtin_amdgcn_mfma_f32_16x16x32_bf16(a[mi], b, acc[mi], 0, 0, 0);
  }
  // part B: agg_h f32 -> bf16 on the fly (k 256..511)
  for (int k0 = 0; k0 < 256; k0 += 32) {
    bf16x8 a[4], b;
    {
      const float* ap = agg_h + (size_t)m * 256 + k0 + q * 8;
      float4 u = *(const float4*)ap;
      float4 v = *(const float4*)(ap + 4);
      uint4 o;
      o.x = pk_bf16(u.x, u.y); o.y = pk_bf16(u.z, u.w);
      o.z = pk_bf16(v.x, v.y); o.w = pk_bf16(v.z, v.w);
      b = *(const bf16x8*)&o;
    }
#pragma unroll
    for (int mi = 0; mi < 4; ++mi)
      a[mi] = *(const bf16x8*)(Wn1T + (size_t)(w * 64 + 16 * mi + r) * 512 + 256 + k0 + q * 8);
#pragma unroll
    for (int mi = 0; mi < 4; ++mi)
      acc[mi] = __builtin_amdgcn_mfma_f32_16x16x32_bf16(a[mi], b, acc[mi], 0, 0, 0);
  }
  __syncthreads();
  // epilogue -> buf[node_local][hidden], b64 writes
#pragma unroll
  for (int mi = 0; mi < 4; ++mi) {
    int ch = w * 64 + 16 * mi + 4 * q;
    float4 bv = *(const float4*)(bn1 + ch);
    float f0 = silu_f(acc[mi][0] + bv.x);
    float f1 = silu_f(acc[mi][1] + bv.y);
    float f2 = silu_f(acc[mi][2] + bv.z);
    float f3 = silu_f(acc[mi][3] + bv.w);
    uint2 o; o.x = pk_bf16(f0, f1); o.y = pk_bf16(f2, f3);
    *(uint2*)(buf + r * KPAD + ch) = o;
  }
  __syncthreads();
  // layer2 -> h_out (float4 stores)
  f32x4 acc2[4];
#pragma unroll
  for (int mi = 0; mi < 4; ++mi) acc2[mi] = (f32x4){0.f, 0.f, 0.f, 0.f};
  mfmaT_k256_b1(Wn2T, 256, 0, buf, w, r, q, acc2);
#pragma unroll
  for (int mi = 0; mi < 4; ++mi) {
    int ch = w * 64 + 16 * mi + 4 * q;
    float4 bv = *(const float4*)(bn2 + ch);
    float4 o;
    o.x = acc2[mi][0] + bv.x;
    o.y = acc2[mi][1] + bv.y;
    o.z = acc2[mi][2] + bv.z;
    o.w = acc2[mi][3] + bv.w;
    *(float4*)(h_out + (size_t)m * 256 + ch) = o;
  }
}

extern "C" void kernel_launch(void* const* d_in, const int* in_sizes, int n_in,
                              void* d_out, int out_size, void* d_ws, size_t ws_size,
                              hipStream_t stream) {
  const float* h     = (const float*)d_in[0];
  const float* coord = (const float*)d_in[1];
  const int*   eidx  = (const int*)d_in[2];
  const float* We1 = (const float*)d_in[3];
  const float* be1 = (const float*)d_in[4];
  const float* We2 = (const float*)d_in[5];
  const float* be2 = (const float*)d_in[6];
  const float* Wn1 = (const float*)d_in[7];
  const float* bn1 = (const float*)d_in[8];
  const float* Wn2 = (const float*)d_in[9];
  const float* bn2 = (const float*)d_in[10];
  const float* Wc1 = (const float*)d_in[11];
  const float* bc1 = (const float*)d_in[12];
  const float* Wc2 = (const float*)d_in[13];
  const float* bc2 = (const float*)d_in[14];

  char* ws = (char*)d_ws;
  float* agg_h = (float*)(ws + 0);          // 10,240,000
  float* agg_c = (float*)(ws + 10240000);   //    120,000
  int*   hist  = (int*)  (ws + 10360000);   //     40,000
  int*   base  = (int*)  (ws + 10400000);   //     40,000
  int*   cursor= (int*)  (ws + 10440000);   //     40,000
  int2*  rc    = (int2*) (ws + 10480000);   //  2,560,000
  bf16* Hb   = (bf16*)(ws + 13040000);      //  5,120,000
  bf16* P    = (bf16*)(ws + 18160000);      //  5,120,000
  bf16* Q    = (bf16*)(ws + 23280000);      //  5,120,000
  bf16* We1T = (bf16*)(ws + 28400000);      //    262,144
  bf16* Wn1T = (bf16*)(ws + 28662144);      //    262,144
  bf16* We2T = (bf16*)(ws + 28924288);      //    131,072
  bf16* Wn2T = (bf16*)(ws + 29055360);      //    131,072
  bf16* Wc1T = (bf16*)(ws + 29186432);      //    131,072

  float* h_out = (float*)d_out;
  float* coord_out = h_out + (size_t)N_NODES * 256;

  hipMemsetAsync(hist, 0, 40000, stream);   // hist only; agg zeroing folded into prep
  prep_kernel<<<14014, 256, 0, stream>>>(h, We1, We2, Wn1, Wn2, Wc1, eidx,
                                         Hb, We1T, Wn1T, We2T, Wn2T, Wc1T, hist,
                                         (float4*)agg_h);
  scan_kernel<<<1, 256, 0, stream>>>(hist, base, cursor);
  scatter_kernel<<<1250, 256, 0, stream>>>(eidx, cursor, rc);
  gemm_pq<<<dim3(625, 2), 256, 0, stream>>>(Hb, We1T, be1, P, Q);
  edge_kernel<<<5000, 256, 0, stream>>>(coord, rc, We1, be2, bc1, Wc2, bc2,
                                        P, Q, We2T, Wc1T, agg_h, agg_c);
  node_kernel<<<625, 256, 0, stream>>>(Hb, agg_h, hist, coord, agg_c,
                                       Wn1T, Wn2T, bn1, bn2, h_out, coord_out);
}